// Round 1
// baseline (2539.324 us; speedup 1.0000x reference)
//
#include <hip/hip_runtime.h>

#define EMB 64

// ---------------- CSR build ----------------

static __global__ void hist_kernel(const int* __restrict__ rows, int* __restrict__ cnt, int nnz) {
    int i = blockIdx.x * blockDim.x + threadIdx.x;
    int stride = gridDim.x * blockDim.x;
    for (; i < nnz; i += stride) atomicAdd(&cnt[rows[i]], 1);
}

// block-level exclusive scan (Hillis-Steele in LDS), 1024 threads/block
static __global__ void scan1_kernel(const int* __restrict__ cnt, int* __restrict__ rp,
                                    int* __restrict__ bsum, int n) {
    __shared__ int sm[1024];
    int tid = threadIdx.x;
    int i = blockIdx.x * 1024 + tid;
    int v = (i < n) ? cnt[i] : 0;
    sm[tid] = v;
    __syncthreads();
    for (int off = 1; off < 1024; off <<= 1) {
        int t = (tid >= off) ? sm[tid - off] : 0;
        __syncthreads();
        sm[tid] += t;
        __syncthreads();
    }
    if (i < n) rp[i] = sm[tid] - v;           // exclusive within block
    if (tid == 1023) bsum[blockIdx.x] = sm[1023];
}

static __global__ void scan2_kernel(int* __restrict__ bsum, int nb) {
    __shared__ int sm[1024];
    int tid = threadIdx.x;
    int v = (tid < nb) ? bsum[tid] : 0;
    sm[tid] = v;
    __syncthreads();
    for (int off = 1; off < 1024; off <<= 1) {
        int t = (tid >= off) ? sm[tid - off] : 0;
        __syncthreads();
        sm[tid] += t;
        __syncthreads();
    }
    if (tid < nb) bsum[tid] = sm[tid] - v;    // exclusive
}

static __global__ void scan3_kernel(int* __restrict__ rp, const int* __restrict__ bsum,
                                    int n, int nnz) {
    int i = blockIdx.x * 1024 + threadIdx.x;
    if (i < n) rp[i] += bsum[blockIdx.x];
    if (i == 0) rp[n] = nnz;
}

static __global__ void scatter_kernel(const int* __restrict__ rows, const int* __restrict__ cols,
                                      const float* __restrict__ vals, const int* __restrict__ rp,
                                      int* __restrict__ fill, int2* __restrict__ csr, int nnz) {
    int i = blockIdx.x * blockDim.x + threadIdx.x;
    int stride = gridDim.x * blockDim.x;
    for (; i < nnz; i += stride) {
        int r = rows[i];
        int p = rp[r] + atomicAdd(&fill[r], 1);
        csr[p] = make_int2(cols[i], __float_as_int(vals[i]));
    }
}

// ---------------- init: x0 = acc = concat(user_emb, item_emb) ----------------

static __global__ void init_kernel(const float4* __restrict__ ue, const float4* __restrict__ ie,
                                   float4* __restrict__ x0, float4* __restrict__ acc,
                                   int nu4, int ntot4) {
    int i = blockIdx.x * blockDim.x + threadIdx.x;
    int stride = gridDim.x * blockDim.x;
    for (; i < ntot4; i += stride) {
        float4 v = (i < nu4) ? ue[i] : ie[i - nu4];
        x0[i] = v;
        acc[i] = v;
    }
}

// ---------------- SpMM: one wave per row, lane = dim ----------------

template <int LAST>
static __global__ __launch_bounds__(256) void spmm_kernel(
    const int2* __restrict__ csr, const int* __restrict__ rp,
    const float* __restrict__ x, float* __restrict__ xn,
    float* __restrict__ acc, int nrows) {
    int wid = blockIdx.x * (blockDim.x >> 6) + (threadIdx.x >> 6);
    if (wid >= nrows) return;
    int lane = threadIdx.x & 63;
    int beg = rp[wid], end = rp[wid + 1];
    float s = 0.f;
    for (int base = beg; base < end; base += 64) {
        int idx = base + lane;
        int2 cv = (idx < end) ? csr[idx] : make_int2(0, 0);  // pad: col=0, val=0
        int rem = end - base;
        if (rem > 64) rem = 64;
        int chunks = (rem + 7) >> 3;
        for (int c = 0; c < chunks; ++c) {
#pragma unroll
            for (int u = 0; u < 8; ++u) {
                int k = (c << 3) + u;
                int col = __shfl(cv.x, k);
                float v = __int_as_float(__shfl(cv.y, k));
                s = fmaf(v, x[col * EMB + lane], s);   // coalesced 256B per edge
            }
        }
    }
    int o = wid * EMB + lane;
    if (LAST) {
        acc[o] = (acc[o] + s) * 0.25f;   // fold final /(L+1)
    } else {
        xn[o] = s;
        acc[o] += s;
    }
}

// ---------------- launch ----------------

extern "C" void kernel_launch(void* const* d_in, const int* in_sizes, int n_in,
                              void* d_out, int out_size, void* d_ws, size_t ws_size,
                              hipStream_t stream) {
    const int* rows = (const int*)d_in[0];
    const int* cols = (const int*)d_in[1];
    const float* vals = (const float*)d_in[2];
    const float* ue = (const float*)d_in[3];
    const float* ie = (const float*)d_in[4];
    float* out = (float*)d_out;

    const int nnz = in_sizes[0];
    const int n_users = in_sizes[3] / EMB;
    const int n_items = in_sizes[4] / EMB;
    const int ntot = n_users + n_items;

    // workspace carve-out (256B aligned)
    char* ws = (char*)d_ws;
    size_t off = 0;
    auto alloc = [&](size_t bytes) -> void* {
        void* p = ws + off;
        off = (off + bytes + 255) & ~(size_t)255;
        return p;
    };
    int* cnt  = (int*)alloc((size_t)ntot * 4);
    int* fill = (int*)alloc((size_t)ntot * 4);
    int* rp   = (int*)alloc((size_t)(ntot + 1) * 4);
    int* bsum = (int*)alloc(1024 * 4);
    int2* csr = (int2*)alloc((size_t)nnz * 8);
    float* x0 = (float*)alloc((size_t)ntot * EMB * 4);
    float* x1 = (float*)alloc((size_t)ntot * EMB * 4);
    (void)ws_size;

    hipMemsetAsync(cnt, 0, (size_t)ntot * 4, stream);
    hipMemsetAsync(fill, 0, (size_t)ntot * 4, stream);

    hist_kernel<<<2048, 256, 0, stream>>>(rows, cnt, nnz);

    int nb = (ntot + 1023) / 1024;   // 196 <= 1024
    scan1_kernel<<<nb, 1024, 0, stream>>>(cnt, rp, bsum, ntot);
    scan2_kernel<<<1, 1024, 0, stream>>>(bsum, nb);
    scan3_kernel<<<nb, 1024, 0, stream>>>(rp, bsum, ntot, nnz);

    scatter_kernel<<<2048, 256, 0, stream>>>(rows, cols, vals, rp, fill, csr, nnz);

    init_kernel<<<2048, 256, 0, stream>>>((const float4*)ue, (const float4*)ie,
                                          (float4*)x0, (float4*)out,
                                          n_users * EMB / 4, ntot * EMB / 4);

    int spmm_blocks = (ntot + 3) / 4;   // 4 waves (rows) per 256-thread block
    spmm_kernel<0><<<spmm_blocks, 256, 0, stream>>>(csr, rp, x0, x1, out, ntot);
    spmm_kernel<0><<<spmm_blocks, 256, 0, stream>>>(csr, rp, x1, x0, out, ntot);
    spmm_kernel<1><<<spmm_blocks, 256, 0, stream>>>(csr, rp, x0, nullptr, out, ntot);
}